// Round 6
// baseline (299.532 us; speedup 1.0000x reference)
//
#include <hip/hip_runtime.h>

// DerivativeRBF: X(512,16), X2(512,16), uls(16), uvar(1) ->
//   K(512,512) | grad_K(8192,512) | hess_K(8192,8192) concat in d_out.
// 286 MB output, ~64 KB input: pure write-BW problem. Fill kernel on this
// buffer: 6.2 TB/s. R3/R4 (thread-owns-(i,j), transposed scatter stores):
// kernel ~107us (~2.7 TB/s), nt flag irrelevant. Theory: DRAM write-stream
// locality. R6: every block writes ONE linear 32KB region; hess values
// computed via 36KB LDS staging per output row; 8736 uniform blocks to
// kill co-residency quantization (4 blocks/CU by LDS).

#define NN 512
#define DD 16
#define NDD 8192
#define GOFF (NN * NN)                 // grad_K offset: 262144 floats
#define HOFF (NN * NN + NDD * NN)      // hess_K offset: 4456448 floats

typedef float fv4 __attribute__((ext_vector_type(4)));
typedef float fv2 __attribute__((ext_vector_type(2)));

__device__ __forceinline__ float softplus_f(float x) {
    return fmaxf(x, 0.0f) + log1pf(expf(-fabsf(x)));   // stable, = jax.nn.softplus
}

__device__ __forceinline__ void load_row16(const float* __restrict__ p, float (&r)[DD]) {
    const fv4* p4 = (const fv4*)p;
    #pragma unroll
    for (int c = 0; c < 4; ++c) {
        fv4 v = p4[c];
        r[c*4+0] = v.x; r[c*4+1] = v.y; r[c*4+2] = v.z; r[c*4+3] = v.w;
    }
}

__global__ __launch_bounds__(256, 4) void drbf_kernel(
    const float* __restrict__ X, const float* __restrict__ X2,
    const float* __restrict__ uls, const float* __restrict__ uvar,
    float* __restrict__ out)
{
    __shared__ float s_il2[DD];    // 1/l^2
    __shared__ float s_h2[DD];     // 0.5/l^2
    __shared__ float s_var;
    __shared__ float sS[DD][NN];   // s_d(i, j) for this block's row i  (32 KB)
    __shared__ float ta[NN];       // -0.25*k*s_a                        (2 KB)
    __shared__ float kk[NN];       // k(i, j)                            (2 KB)

    const int t = threadIdx.x;
    if (t < DD) {
        float ls = softplus_f(uls[t]);
        float i2 = 1.0f / (ls * ls);
        s_il2[t] = i2;
        s_h2[t]  = 0.5f * i2;
    }
    if (t == DD) s_var = softplus_f(uvar[0]);
    __syncthreads();
    const float var = s_var;
    const int bx = blockIdx.x;

    if (bx < 8192) {
        // ---- hess_K: block owns ONE output row r = a*512+i (32 KB linear).
        const int a = bx >> 9;          // 0..15
        const int i = bx & 511;         // 0..511
        const float h2a = s_h2[a];

        // Thread t computes cols j = 2t, 2t+1.
        float xj0[DD], xj1[DD], xi[DD];
        load_row16(X + (2*t)     * DD, xj0);
        load_row16(X + (2*t + 1) * DD, xj1);
        load_row16(X + i * DD, xi);     // lane-uniform, L1 broadcast

        float sq0 = 0.f, sq1 = 0.f, sa0 = 0.f, sa1 = 0.f;
        #pragma unroll
        for (int d = 0; d < DD; ++d) {
            float il2 = s_il2[d];
            float d0 = xi[d] - xj0[d]; float s0 = d0 * il2; sq0 += s0 * d0;
            float d1 = xi[d] - xj1[d]; float s1 = d1 * il2; sq1 += s1 * d1;
            if (d == a) { sa0 = s0; sa1 = s1; }           // uniform cond, cndmask
            ((fv2*)&sS[d][0])[t] = (fv2){s0, s1};         // 2-way bank alias: free
        }
        float k0 = var * expf(-0.25f * sq0);
        float k1 = var * expf(-0.25f * sq1);
        ((fv2*)ta)[t] = (fv2){-0.25f * k0 * sa0, -0.25f * k1 * sa1};
        ((fv2*)kk)[t] = (fv2){k0, k1};
        __syncthreads();

        // phase 2: stream the 32KB row out linearly, 8 x 4KB wave-fronts.
        fv4* row = (fv4*)(out + HOFF + (size_t)bx * NDD);
        #pragma unroll
        for (int r = 0; r < 8; ++r) {
            int c4 = r * 256 + t;        // float4 index within row (0..2047)
            int b  = c4 >> 7;            // output col block 0..15
            int j4 = c4 & 127;           // float4 index within col block
            fv4 sB = ((const fv4*)&sS[b][0])[j4];   // contiguous ds_read_b128
            fv4 tv = ((const fv4*)ta)[j4];
            fv4 kv = ((const fv4*)kk)[j4];
            float dm = (b == a) ? h2a : 0.0f;
            row[c4] = tv * sB + kv * dm;
        }
    } else if (bx < 8192 + 512) {
        // ---- grad_K: block owns 16 consecutive rows of one d-slab (32 KB linear).
        const int beta = bx - 8192;
        const int dblk = beta >> 5;          // 0..15
        const int n0   = (beta & 31) * 16;   // 16 rows

        float x2a[DD], x2b[DD];              // X2 rows for cols t, t+256
        load_row16(X2 + t * DD, x2a);
        load_row16(X2 + (t + 256) * DD, x2b);

        for (int n = n0; n < n0 + 16; ++n) {
            float xn[DD];
            load_row16(X + n * DD, xn);      // lane-uniform
            float sqa = 0.f, sqb = 0.f, sda = 0.f, sdb = 0.f;
            #pragma unroll
            for (int d = 0; d < DD; ++d) {
                float il2 = s_il2[d];
                float da = xn[d] - x2a[d]; float sa_ = da * il2; sqa += sa_ * da;
                float db = xn[d] - x2b[d]; float sb_ = db * il2; sqb += sb_ * db;
                if (d == dblk) { sda = sa_; sdb = sb_; }
            }
            float ka = var * expf(-0.25f * sqa);
            float kb = var * expf(-0.25f * sqb);
            float* rowp = out + GOFF + (size_t)(dblk * NN + n) * NN;
            rowp[t]       = -0.5f * sda * ka;
            rowp[t + 256] = -0.5f * sdb * kb;
        }
    } else {
        // ---- K: 32 blocks x 16 rows (32 KB linear each).
        const int beta = bx - 8192 - 512;
        const int n0 = beta * 16;

        float x2a[DD], x2b[DD];
        load_row16(X2 + t * DD, x2a);
        load_row16(X2 + (t + 256) * DD, x2b);

        for (int n = n0; n < n0 + 16; ++n) {
            float xn[DD];
            load_row16(X + n * DD, xn);
            float sqa = 0.f, sqb = 0.f;
            #pragma unroll
            for (int d = 0; d < DD; ++d) {
                float il2 = s_il2[d];
                float da = xn[d] - x2a[d]; sqa += da * da * il2;
                float db = xn[d] - x2b[d]; sqb += db * db * il2;
            }
            float* rowp = out + (size_t)n * NN;
            rowp[t]       = var * expf(-0.25f * sqa);
            rowp[t + 256] = var * expf(-0.25f * sqb);
        }
    }
}

extern "C" void kernel_launch(void* const* d_in, const int* in_sizes, int n_in,
                              void* d_out, int out_size, void* d_ws, size_t ws_size,
                              hipStream_t stream) {
    const float* X    = (const float*)d_in[0];
    const float* X2   = (const float*)d_in[1];
    const float* uls  = (const float*)d_in[2];
    const float* uvar = (const float*)d_in[3];
    float* out = (float*)d_out;
    // 8192 hess + 512 grad + 32 K = 8736 uniform blocks, each writing 32KB
    // linearly. LDS 36KB -> 4 blocks/CU co-resident, ~8.5 scheduling rounds.
    drbf_kernel<<<dim3(8736), dim3(256), 0, stream>>>(X, X2, uls, uvar, out);
}